// Round 7
// baseline (28.377 us; speedup 1.0000x reference)
//
#include <hip/hip_runtime.h>
#include <math.h>

#define SZ 28

__constant__ int c_fy[10] = {4,4,4,14,14,14,24,24,24,12};
__constant__ int c_fx[10] = {4,14,24,4,14,24,4,14,24,12};

typedef __attribute__((ext_vector_type(4)))  float    f32x4;
typedef __attribute__((ext_vector_type(16))) float    f32x16;
typedef __attribute__((ext_vector_type(8)))  _Float16 f16x8;

// ---------------------------------------------------------------------------
// Prep (unchanged from round 6 — verified): f16 MFMA B-fragments.
// B-frag for mfma_f32_32x32x16_f16: lane l holds B[k=s*16+(l>>5)*8+j][col=l&31]
// w2[s*512 + ((b*32)+v)*8 + j], b=(k>>3)&1; cols v: 2p=Re(p), 2p+1=Im(p), v>=20 zero.
// ---------------------------------------------------------------------------
__global__ __launch_bounds__(784) void prep_weights(const float* __restrict__ phase,
                                                    _Float16* __restrict__ w2) {
    __shared__ float tr[SZ][SZ], ti[SZ][SZ];
    __shared__ float g1r[SZ], g1i[SZ];
    const int tid = threadIdx.x;                    // 0..783 = pixel k
    {
        const int t = tid / SZ, k = tid % SZ;
        const int m = (k <= SZ / 2) ? k : SZ - k;
        int num = (14 * k * t - m * m) % 392; if (num < 0) num += 392;
        float s, c;
        sincosf((float)num * (6.283185307179586f / 392.0f), &s, &c);
        tr[t][k] = c; ti[t][k] = s;
    }
    __syncthreads();
    if (tid < SZ) {
        float ar = 0.f, ai = 0.f;
        for (int k = 0; k < SZ; ++k) { ar += tr[tid][k]; ai += ti[tid][k]; }
        g1r[tid] = ar / 28.f; g1i[tid] = ai / 28.f;
    }
    __syncthreads();
    float Wv[20];
    {
        const int y = tid / SZ, x = tid % SZ;
        float sp, cp; sincosf(phase[tid], &sp, &cp);
        #pragma unroll
        for (int p = 0; p < 10; ++p) {
            const int dy = (c_fy[p] - y + SZ) % SZ;
            const int dx = (c_fx[p] - x + SZ) % SZ;
            const float Gr = g1r[dy] * g1r[dx] - g1i[dy] * g1i[dx];
            const float Gi = g1r[dy] * g1i[dx] + g1i[dy] * g1r[dx];
            Wv[p]      = cp * Gr - sp * Gi;          // Re
            Wv[10 + p] = cp * Gi + sp * Gr;          // Im
        }
    }
    {
        const int k = tid;
        const int s = k >> 4, b = (k >> 3) & 1, j = k & 7;
        #pragma unroll
        for (int v = 0; v < 32; ++v) {
            float val = 0.f;
            if (v < 20) val = (v & 1) ? Wv[10 + (v >> 1)] : Wv[v >> 1];
            w2[s * 512 + (b * 32 + v) * 8 + j] = (_Float16)val;
        }
    }
}

// ---------------------------------------------------------------------------
// Barrierless MFMA GEMM. Block = 256 thr = 4 waves over ONE 32-row mtile;
// wave q owns ksteps [13q, 13q+nk) (nk = 13,13,13,10). Each wave:
//   - loads its 13 B-fragments from w2 (L2-hot) into VGPRs upfront,
//   - streams x per kstep (2 coalesced f4/lane, 3-deep reg prefetch),
//   - cvt_pkrtz -> private 2x1KB LDS double-buffer (XOR-swizzled), ds_read
//     the A-fragment, one mfma_32x32x16_f16 per kstep.
// No __syncthreads in the loop (producer==consumer per wave; lgkmcnt orders).
// One barrier at the end for the 4-way acc reduction + |.|^2 epilogue.
// ---------------------------------------------------------------------------
__global__ __launch_bounds__(256) void focus_gemm(const float* __restrict__ x,
                                                  const _Float16* __restrict__ w2,
                                                  float* __restrict__ out) {
    __shared__ char stage[4][2][1024];               // per-wave double buffers
    __shared__ float red[3][64][17];                 // epilogue partials

    const int tid  = threadIdx.x;
    const int lane = tid & 63;
    const int q = __builtin_amdgcn_readfirstlane(tid >> 6);  // 0..3
    const int row0 = blockIdx.x * 32;
    const int s0 = 13 * q;
    const int nk = (q == 3) ? 10 : 13;

    f32x16 acc;
    #pragma unroll
    for (int i = 0; i < 16; ++i) acc[i] = 0.f;

    // ---- B fragments upfront (guarded, statically indexed) ----
    f16x8 b[13];
    #pragma unroll
    for (int i = 0; i < 13; ++i)
        if (i < nk) b[i] = *(const f16x8*)(w2 + (size_t)(s0 + i) * 512 + lane * 8);

    char* const myb = &stage[q][0][0];

    // slot = i2*64+lane -> r = i2*16 + (lane>>2), c4 = lane&3 (4 f4-cols/kstep)
    auto ldA = [&](f32x4* v, int sg) {
        const f32x4* x4 = (const f32x4*)x;
        #pragma unroll
        for (int i2 = 0; i2 < 2; ++i2) {
            const int r = i2 * 16 + (lane >> 2);
            v[i2] = x4[(size_t)(row0 + r) * 196 + sg * 4 + (lane & 3)];
        }
    };
    // f32x4 -> 4xf16 at byte (slot*8) ^ ((r&7)<<4)  (write-permutation, conflict-free)
    auto writeA = [&](char* buf, const f32x4* v) {
        #pragma unroll
        for (int i2 = 0; i2 < 2; ++i2) {
            auto lo = __builtin_amdgcn_cvt_pkrtz(v[i2].x, v[i2].y);
            auto hi = __builtin_amdgcn_cvt_pkrtz(v[i2].z, v[i2].w);
            uint2 d;
            d.x = __builtin_bit_cast(unsigned int, lo);
            d.y = __builtin_bit_cast(unsigned int, hi);
            const int adr = ((i2 * 64 + lane) * 8) ^ ((((lane >> 2)) & 7) << 4);
            *(uint2*)(buf + adr) = d;
        }
    };
    // lane reads row r=lane&31, k-half h=lane>>5: (r*32 + h*16) ^ ((r&7)<<4)
    auto readA = [&](const char* buf) -> f16x8 {
        const int r = lane & 31, h = lane >> 5;
        const int adr = (r * 32 + h * 16) ^ ((r & 7) << 4);
        return *(const f16x8*)(buf + adr);
    };

    f32x4 va0[2], va1[2], va2[2];                    // 3-deep prefetch (static)
    ldA(va0, s0 + 0);
    ldA(va1, s0 + 1);
    ldA(va2, s0 + 2);
    writeA(myb, va0);                                // buf0 <- kstep s0

    #pragma unroll
    for (int i = 0; i < 13; ++i) {
        // issue loads for kstep i+3 into the set freed last iteration
        if (i + 3 < nk) {
            if ((i % 3) == 0)      ldA(va0, s0 + i + 3);
            else if ((i % 3) == 1) ldA(va1, s0 + i + 3);
            else                   ldA(va2, s0 + i + 3);
        }
        if (i < nk) {
            f16x8 af = readA(myb + (i & 1) * 1024);
            acc = __builtin_amdgcn_mfma_f32_32x32x16_f16(af, b[i], acc, 0, 0, 0);
        }
        if (i + 1 < nk) {
            char* nb = myb + ((i + 1) & 1) * 1024;
            if (((i + 1) % 3) == 0)      writeA(nb, va0);
            else if (((i + 1) % 3) == 1) writeA(nb, va1);
            else                         writeA(nb, va2);
        }
    }

    // ---- 4-way reduction + |.|^2 epilogue (single barrier) ----
    if (q > 0) {
        #pragma unroll
        for (int i = 0; i < 16; ++i) red[q - 1][lane][i] = acc[i];
    }
    __syncthreads();
    if (q == 0) {
        const int col = lane & 31;
        #pragma unroll
        for (int i = 0; i < 16; ++i) {
            const float sum = acc[i] + red[0][lane][i] + red[1][lane][i]
                            + red[2][lane][i];
            const float sq = sum * sum;
            const float tot = sq + __shfl_xor(sq, 1, 64);
            if ((col & 1) == 0 && col < 20) {
                const int r = (i & 3) + 8 * (i >> 2) + 4 * (lane >> 5);
                out[(size_t)(row0 + r) * 10 + (col >> 1)] = tot;
            }
        }
    }
}

extern "C" void kernel_launch(void* const* d_in, const int* in_sizes, int n_in,
                              void* d_out, int out_size, void* d_ws, size_t ws_size,
                              hipStream_t stream) {
    const float* x     = (const float*)d_in[0];   // [32768,1,28,28] f32
    const float* phase = (const float*)d_in[1];   // [28,28] f32
    float* out = (float*)d_out;                   // [32768,10] f32
    _Float16* w2 = (_Float16*)d_ws;               // 49*512 f16 = 50 KB

    hipLaunchKernelGGL(prep_weights, dim3(1), dim3(SZ * SZ), 0, stream, phase, w2);

    const int B = in_sizes[0] / (SZ * SZ);        // 32768
    hipLaunchKernelGGL(focus_gemm, dim3(B / 32), dim3(256), 0, stream, x, w2, out);
}

// Round 8
// 27.464 us; speedup vs baseline: 1.0333x; 1.0333x over previous
//
#include <hip/hip_runtime.h>
#include <math.h>

#define SZ 28

__constant__ int c_fy[10] = {4,4,4,14,14,14,24,24,24,12};
__constant__ int c_fx[10] = {4,14,24,4,14,24,4,14,24,12};

typedef __attribute__((ext_vector_type(4)))  float    f32x4;
typedef __attribute__((ext_vector_type(16))) float    f32x16;
typedef __attribute__((ext_vector_type(8)))  _Float16 f16x8;

// ---------------------------------------------------------------------------
// Prep, parallelized: 49 blocks, one per kstep s. Each block computes the
// 28-pt DFT table (redundantly — it's ~300 cycles), then threads 0..15 build
// the 16 pixels k = 16s..16s+15 and write the contiguous 1 KB w2 slab.
// B-frag for mfma_f32_32x32x16_f16: lane l holds B[k=s*16+(l>>5)*8+j][col=l&31]
// w2[s*512 + ((b*32)+v)*8 + j], b=(k>>3)&1; cols v: 2p=Re(p), 2p+1=Im(p).
// ---------------------------------------------------------------------------
__global__ __launch_bounds__(784) void prep_weights(const float* __restrict__ phase,
                                                    _Float16* __restrict__ w2) {
    __shared__ float tr[SZ][SZ], ti[SZ][SZ];
    __shared__ float g1r[SZ], g1i[SZ];
    const int tid = threadIdx.x;                    // 0..783
    const int s = blockIdx.x;                       // kstep 0..48
    {
        const int t = tid / SZ, k = tid % SZ;
        const int m = (k <= SZ / 2) ? k : SZ - k;
        int num = (14 * k * t - m * m) % 392; if (num < 0) num += 392;
        float sn, cs;
        sincosf((float)num * (6.283185307179586f / 392.0f), &sn, &cs);
        tr[t][k] = cs; ti[t][k] = sn;
    }
    __syncthreads();
    if (tid < SZ) {
        float ar = 0.f, ai = 0.f;
        for (int k = 0; k < SZ; ++k) { ar += tr[tid][k]; ai += ti[tid][k]; }
        g1r[tid] = ar / 28.f; g1i[tid] = ai / 28.f;
    }
    __syncthreads();
    if (tid < 16) {
        const int k = s * 16 + tid;                 // pixel 0..783
        const int y = k / SZ, x = k % SZ;
        float Wv[20];
        float sp, cp; sincosf(phase[k], &sp, &cp);
        #pragma unroll
        for (int p = 0; p < 10; ++p) {
            const int dy = (c_fy[p] - y + SZ) % SZ;
            const int dx = (c_fx[p] - x + SZ) % SZ;
            const float Gr = g1r[dy] * g1r[dx] - g1i[dy] * g1i[dx];
            const float Gi = g1r[dy] * g1i[dx] + g1i[dy] * g1r[dx];
            Wv[p]      = cp * Gr - sp * Gi;          // Re
            Wv[10 + p] = cp * Gi + sp * Gr;          // Im
        }
        const int b = tid >> 3, j = tid & 7;
        #pragma unroll
        for (int v = 0; v < 32; ++v) {
            float val = 0.f;
            if (v < 20) val = (v & 1) ? Wv[10 + (v >> 1)] : Wv[v >> 1];
            w2[s * 512 + (b * 32 + v) * 8 + j] = (_Float16)val;
        }
    }
}

// ---------------------------------------------------------------------------
// Main MFMA GEMM (round-6 core, best measured): C[64x32] per block, then
// out[row][p] = C[row][2p]^2 + C[row][2p+1]^2 (adjacent-lane shfl_xor).
// Block = 256 thr = 4 waves: wave q -> mtile m=q>>1 (32 rows), K-parity p=q&1.
// x reg-staged f32->f16 (cvt_pkrtz) into fragment-order LDS (lane^s swizzle),
// double-buffered, 1 chunk ahead. W via global_load_lds (16B), lane-linear.
// LDS: bufA 2x14336 + bufB 2x7168 = 43008 B.
// ---------------------------------------------------------------------------
__device__ static inline void gload_lds16(const void* src, char* lds_dst) {
    __builtin_amdgcn_global_load_lds(
        (const __attribute__((address_space(1))) void*)src,
        (__attribute__((address_space(3))) void*)lds_dst, 16, 0, 0);
}

__global__ __launch_bounds__(256, 3) void focus_gemm(const float* __restrict__ x,
                                                     const _Float16* __restrict__ w2,
                                                     float* __restrict__ out) {
    __shared__ char smem[43008];
    const int tid  = threadIdx.x;
    const int lane = tid & 63;
    const int q = __builtin_amdgcn_readfirstlane(tid >> 6);  // 0..3
    const int m = q >> 1;                                    // mtile
    const int p = q & 1;                                     // kstep half
    const int row0 = blockIdx.x * 64;

    f32x16 acc;
    #pragma unroll
    for (int i = 0; i < 16; ++i) acc[i] = 0.f;

    char* const bA0 = smem;                 // 2 x 14336
    char* const bB0 = smem + 28672;         // 2 x 7168

    auto stageB = [&](int c) {
        for (int s = q; s < 7; s += 4)
            gload_lds16(w2 + (c * 7 + s) * 512 + lane * 8,
                        bB0 + (c & 1) * 7168 + s * 1024);
    };
    auto loadA = [&](f32x4* v, int c) {
        const f32x4* x4 = (const f32x4*)x;
        #pragma unroll
        for (int i = 0; i < 7; ++i) {
            const int g = i * 256 + tid;
            const int r = g / 28, c4 = g % 28;
            v[i] = x4[(size_t)(row0 + r) * 196 + c * 28 + c4];
        }
    };
    auto writeA = [&](const f32x4* v, int c) {
        char* buf = bA0 + (c & 1) * 14336;
        #pragma unroll
        for (int i = 0; i < 7; ++i) {
            const int g = i * 256 + tid;
            const int r = g / 28, c4 = g % 28;
            const int s = c4 >> 2, b = (c4 >> 1) & 1;
            const int mt = r >> 5;
            const int ln = ((r & 31) + (b << 5)) ^ s;
            auto lo = __builtin_amdgcn_cvt_pkrtz(v[i].x, v[i].y);
            auto hi = __builtin_amdgcn_cvt_pkrtz(v[i].z, v[i].w);
            uint2 d;
            d.x = __builtin_bit_cast(unsigned int, lo);
            d.y = __builtin_bit_cast(unsigned int, hi);
            *(uint2*)(buf + ((s * 2 + mt) * 64 + ln) * 16 + (c4 & 1) * 8) = d;
        }
    };
    auto compute = [&](int c) {
        char* bA = bA0 + (c & 1) * 14336;
        char* bB = bB0 + (c & 1) * 7168;
        const int sbeg = p ? 4 : 0, send = p ? 7 : 4;
        for (int s = sbeg; s < send; ++s) {
            f16x8 a = *(const f16x8*)(bA + ((s * 2 + m) * 64 + (lane ^ s)) * 16);
            f16x8 b = *(const f16x8*)(bB + s * 1024 + lane * 16);
            acc = __builtin_amdgcn_mfma_f32_32x32x16_f16(a, b, acc, 0, 0, 0);
        }
    };

    f32x4 v[7];
    loadA(v, 0); stageB(0); writeA(v, 0);
    for (int c = 0; c < 7; ++c) {
        __syncthreads();                         // publishes chunk c buffers
        if (c < 6) { loadA(v, c + 1); stageB(c + 1); }
        compute(c);
        if (c < 6) writeA(v, c + 1);
    }

    __syncthreads();
    float* red = (float*)smem;                   // [2][64][17]
    if (p == 1) {
        #pragma unroll
        for (int i = 0; i < 16; ++i) red[(m * 64 + lane) * 17 + i] = acc[i];
    }
    __syncthreads();
    if (p == 0) {
        const int col = lane & 31;
        #pragma unroll
        for (int i = 0; i < 16; ++i) {
            const float sum = acc[i] + red[(m * 64 + lane) * 17 + i];
            const float sq = sum * sum;
            const float tot = sq + __shfl_xor(sq, 1, 64);
            if ((col & 1) == 0 && col < 20) {
                const int r = (i & 3) + 8 * (i >> 2) + 4 * (lane >> 5);
                out[(size_t)(row0 + m * 32 + r) * 10 + (col >> 1)] = tot;
            }
        }
    }
}

extern "C" void kernel_launch(void* const* d_in, const int* in_sizes, int n_in,
                              void* d_out, int out_size, void* d_ws, size_t ws_size,
                              hipStream_t stream) {
    const float* x     = (const float*)d_in[0];   // [32768,1,28,28] f32
    const float* phase = (const float*)d_in[1];   // [28,28] f32
    float* out = (float*)d_out;                   // [32768,10] f32
    _Float16* w2 = (_Float16*)d_ws;               // 49*512 f16 = 50 KB

    hipLaunchKernelGGL(prep_weights, dim3(49), dim3(SZ * SZ), 0, stream, phase, w2);

    const int B = in_sizes[0] / (SZ * SZ);        // 32768
    hipLaunchKernelGGL(focus_gemm, dim3(B / 64), dim3(256), 0, stream, x, w2, out);
}

// Round 9
// 27.095 us; speedup vs baseline: 1.0473x; 1.0136x over previous
//
#include <hip/hip_runtime.h>
#include <math.h>

#define SZ 28

__constant__ int c_fy[10] = {4,4,4,14,14,14,24,24,24,12};
__constant__ int c_fx[10] = {4,14,24,4,14,24,4,14,24,12};

typedef __attribute__((ext_vector_type(4)))  float    f32x4;
typedef __attribute__((ext_vector_type(16))) float    f32x16;
typedef __attribute__((ext_vector_type(8)))  _Float16 f16x8;

// ---------------------------------------------------------------------------
// Prep (R8 version, verified): 49 blocks, one per kstep s; each computes the
// 28-pt DFT table redundantly, threads 0..15 emit the 1 KB w2 slab.
// B-frag for mfma_f32_32x32x16_f16: lane l holds B[k=s*16+(l>>5)*8+j][col=l&31]
// w2[s*512 + ((b*32)+v)*8 + j], b=(k>>3)&1; cols v: 2p=Re(p), 2p+1=Im(p).
// ---------------------------------------------------------------------------
__global__ __launch_bounds__(784) void prep_weights(const float* __restrict__ phase,
                                                    _Float16* __restrict__ w2) {
    __shared__ float tr[SZ][SZ], ti[SZ][SZ];
    __shared__ float g1r[SZ], g1i[SZ];
    const int tid = threadIdx.x;                    // 0..783
    const int s = blockIdx.x;                       // kstep 0..48
    {
        const int t = tid / SZ, k = tid % SZ;
        const int m = (k <= SZ / 2) ? k : SZ - k;
        int num = (14 * k * t - m * m) % 392; if (num < 0) num += 392;
        float sn, cs;
        sincosf((float)num * (6.283185307179586f / 392.0f), &sn, &cs);
        tr[t][k] = cs; ti[t][k] = sn;
    }
    __syncthreads();
    if (tid < SZ) {
        float ar = 0.f, ai = 0.f;
        for (int k = 0; k < SZ; ++k) { ar += tr[tid][k]; ai += ti[tid][k]; }
        g1r[tid] = ar / 28.f; g1i[tid] = ai / 28.f;
    }
    __syncthreads();
    if (tid < 16) {
        const int k = s * 16 + tid;                 // pixel 0..783
        const int y = k / SZ, x = k % SZ;
        float Wv[20];
        float sp, cp; sincosf(phase[k], &sp, &cp);
        #pragma unroll
        for (int p = 0; p < 10; ++p) {
            const int dy = (c_fy[p] - y + SZ) % SZ;
            const int dx = (c_fx[p] - x + SZ) % SZ;
            const float Gr = g1r[dy] * g1r[dx] - g1i[dy] * g1i[dx];
            const float Gi = g1r[dy] * g1i[dx] + g1i[dy] * g1r[dx];
            Wv[p]      = cp * Gr - sp * Gi;          // Re
            Wv[10 + p] = cp * Gi + sp * Gr;          // Im
        }
        const int b = tid >> 3, j = tid & 7;
        #pragma unroll
        for (int v = 0; v < 32; ++v) {
            float val = 0.f;
            if (v < 20) val = (v & 1) ? Wv[10 + (v >> 1)] : Wv[v >> 1];
            w2[s * 512 + (b * 32 + v) * 8 + j] = (_Float16)val;
        }
    }
}

// ---------------------------------------------------------------------------
// Main MFMA GEMM — R6 core widened to 8 waves for occupancy (4 waves/SIMD):
// block = 512 thr = 8 waves = (m in 0..1 mtile) x (kq in 0..3 kstep quarter,
// split {2,2,2,1} of the chunk's 7 ksteps). 64 rows/block, grid 512.
// x reg-staged f32->f16 (cvt_pkrtz) into fragment-order LDS (lane^s swizzle),
// double-buffered, 1 chunk ahead. W via global_load_lds (1KB/wave).
// LDS: bufA 2x14336 + bufB 2x7168 = 43008 B.
// ---------------------------------------------------------------------------
__device__ static inline void gload_lds16(const void* src, char* lds_dst) {
    __builtin_amdgcn_global_load_lds(
        (const __attribute__((address_space(1))) void*)src,
        (__attribute__((address_space(3))) void*)lds_dst, 16, 0, 0);
}

__global__ __launch_bounds__(512) void focus_gemm(const float* __restrict__ x,
                                                  const _Float16* __restrict__ w2,
                                                  float* __restrict__ out) {
    __shared__ char smem[43008];
    const int tid  = threadIdx.x;
    const int lane = tid & 63;
    const int w = __builtin_amdgcn_readfirstlane(tid >> 6);  // 0..7
    const int m = w >> 2;                                    // mtile
    const int kq = w & 3;                                    // kstep quarter
    const int row0 = blockIdx.x * 64;

    f32x16 acc;
    #pragma unroll
    for (int i = 0; i < 16; ++i) acc[i] = 0.f;

    char* const bA0 = smem;                 // 2 x 14336
    char* const bB0 = smem + 28672;         // 2 x 7168

    auto stageB = [&](int c) {
        if (w < 7)
            gload_lds16(w2 + (c * 7 + w) * 512 + lane * 8,
                        bB0 + (c & 1) * 7168 + w * 1024);
    };
    auto loadA = [&](f32x4* v, int c) {
        const f32x4* x4 = (const f32x4*)x;
        #pragma unroll
        for (int i = 0; i < 4; ++i) {
            const int g = i * 512 + tid;
            if (g < 1792) {
                const int r = g / 28, c4 = g % 28;
                v[i] = x4[(size_t)(row0 + r) * 196 + c * 28 + c4];
            }
        }
    };
    auto writeA = [&](const f32x4* v, int c) {
        char* buf = bA0 + (c & 1) * 14336;
        #pragma unroll
        for (int i = 0; i < 4; ++i) {
            const int g = i * 512 + tid;
            if (g < 1792) {
                const int r = g / 28, c4 = g % 28;
                const int s = c4 >> 2, b = (c4 >> 1) & 1;
                const int mt = r >> 5;
                const int ln = ((r & 31) + (b << 5)) ^ s;
                auto lo = __builtin_amdgcn_cvt_pkrtz(v[i].x, v[i].y);
                auto hi = __builtin_amdgcn_cvt_pkrtz(v[i].z, v[i].w);
                uint2 d;
                d.x = __builtin_bit_cast(unsigned int, lo);
                d.y = __builtin_bit_cast(unsigned int, hi);
                *(uint2*)(buf + ((s * 2 + mt) * 64 + ln) * 16 + (c4 & 1) * 8) = d;
            }
        }
    };
    auto compute = [&](int c) {
        char* bA = bA0 + (c & 1) * 14336;
        char* bB = bB0 + (c & 1) * 7168;
        const int sbeg = 2 * kq, send = (kq == 3) ? 7 : 2 * kq + 2;
        for (int s = sbeg; s < send; ++s) {
            f16x8 a = *(const f16x8*)(bA + ((s * 2 + m) * 64 + (lane ^ s)) * 16);
            f16x8 b = *(const f16x8*)(bB + s * 1024 + lane * 16);
            acc = __builtin_amdgcn_mfma_f32_32x32x16_f16(a, b, acc, 0, 0, 0);
        }
    };

    f32x4 v[4];
    stageB(0); loadA(v, 0); writeA(v, 0);
    for (int c = 0; c < 7; ++c) {
        __syncthreads();                         // publishes chunk c buffers
        if (c < 6) { stageB(c + 1); loadA(v, c + 1); }
        compute(c);
        if (c < 6) writeA(v, c + 1);
    }

    // ---- 4-way K reduction per mtile + |.|^2 epilogue ----
    __syncthreads();
    float* red = (float*)smem;                   // [2][3][64][17] = 25.5 KB
    if (kq > 0) {
        #pragma unroll
        for (int i = 0; i < 16; ++i)
            red[((m * 3 + (kq - 1)) * 64 + lane) * 17 + i] = acc[i];
    }
    __syncthreads();
    if (kq == 0) {
        const int col = lane & 31;
        #pragma unroll
        for (int i = 0; i < 16; ++i) {
            const float sum = acc[i]
                + red[((m * 3 + 0) * 64 + lane) * 17 + i]
                + red[((m * 3 + 1) * 64 + lane) * 17 + i]
                + red[((m * 3 + 2) * 64 + lane) * 17 + i];
            const float sq = sum * sum;
            const float tot = sq + __shfl_xor(sq, 1, 64);
            if ((col & 1) == 0 && col < 20) {
                const int r = (i & 3) + 8 * (i >> 2) + 4 * (lane >> 5);
                out[(size_t)(row0 + m * 32 + r) * 10 + (col >> 1)] = tot;
            }
        }
    }
}

extern "C" void kernel_launch(void* const* d_in, const int* in_sizes, int n_in,
                              void* d_out, int out_size, void* d_ws, size_t ws_size,
                              hipStream_t stream) {
    const float* x     = (const float*)d_in[0];   // [32768,1,28,28] f32
    const float* phase = (const float*)d_in[1];   // [28,28] f32
    float* out = (float*)d_out;                   // [32768,10] f32
    _Float16* w2 = (_Float16*)d_ws;               // 49*512 f16 = 50 KB

    hipLaunchKernelGGL(prep_weights, dim3(49), dim3(SZ * SZ), 0, stream, phase, w2);

    const int B = in_sizes[0] / (SZ * SZ);        // 32768
    hipLaunchKernelGGL(focus_gemm, dim3(B / 64), dim3(512), 0, stream, x, w2, out);
}